// Round 5
// baseline (297.446 us; speedup 1.0000x reference)
//
#include <hip/hip_runtime.h>
#include <stdint.h>

#define HW 4096
#define CCH 256
#define BPL (CCH * HW)          // per-batch plane elems
#define LSTR 264                // LDS Bs row stride in shorts (256+8 pad; 528B = 16B-aligned)
#define TILE 64                 // conv px-tile (best measured per-kernel: R3). Each block now
                                //  processes 2 consecutive tiles with reg-prefetch of tile1.
#define NT 4                    // n-tiles per wave (TILE/16)
#define DSTR 84                 // dw bf16 tile row stride in shorts (168B): quarter-wave b64
                                //  reads span one contiguous 128B wrap -> conflict-free.

typedef __attribute__((ext_vector_type(8))) short short8;
typedef __attribute__((ext_vector_type(4))) float floatx4;
typedef unsigned short ushort_t;

__device__ inline ushort_t f2bf(float f) {
    union { float f; unsigned int u; } v; v.f = f;
    unsigned int r = v.u + 0x7FFFu + ((v.u >> 16) & 1u);   // RNE
    return (ushort_t)(r >> 16);
}
// unpack a dword holding 2 bf16 (little-endian: low short = lower col) to 2 floats
__device__ inline void up2(unsigned int d, float* w) {
    union { unsigned int u; float f; } lo, hi;
    lo.u = d << 16; hi.u = d & 0xffff0000u;
    w[0] = lo.f; w[1] = hi.f;
}

// MFMA A-fragment packed weight layout: for 16x16x32 bf16, lane (quad*16+L) of
// wave w holds A[row=cout][k] with cout = w*64 + mt*16 + L, k = kt*32 + quad*8 + e.
// Each wave fragment load = 64 lanes x 16B CONTIGUOUS (1KB). [worth ~14us, R1]
__device__ inline int wpack(int c, int t) {
    const int w  = c >> 6, mt = (c >> 4) & 3, L = c & 15;
    const int kt = t >> 5, quad = (t >> 3) & 3, e = t & 7;
    return ((((w * 8 + kt) * 4 + mt) * 64 + quad * 16 + L) * 8 + e);
}

// ---------------------------------------------------------------------------
// prep: weights->bf16 (fragment-packed), combined dw 9x9 (chunked layout),
// folded BN params. WcP[c][128]: slots 0..44 = dy 0..4 (dy*9+dx), 64..99 = dy 5..8.
__global__ void prep_kernel(
    const float* __restrict__ pre_w, const float* __restrict__ pw_w, const float* __restrict__ post_w,
    const float* __restrict__ g1, const float* __restrict__ b1, const float* __restrict__ m1, const float* __restrict__ v1,
    const float* __restrict__ g2, const float* __restrict__ b2, const float* __restrict__ m2, const float* __restrict__ v2,
    const float* __restrict__ g3, const float* __restrict__ b3, const float* __restrict__ m3, const float* __restrict__ v3,
    const float* __restrict__ w3d, const float* __restrict__ b3d,
    const float* __restrict__ w5d, const float* __restrict__ b5d,
    const float* __restrict__ w7d, const float* __restrict__ b7d,
    const float* __restrict__ w9d, const float* __restrict__ b9d,
    ushort_t* __restrict__ w1b, ushort_t* __restrict__ w2b, ushort_t* __restrict__ w3b,
    float* __restrict__ WcP, float* __restrict__ biasc,
    float* __restrict__ sc1, float* __restrict__ sh1,
    float* __restrict__ sc2, float* __restrict__ sh2,
    float* __restrict__ sc3, float* __restrict__ sh3)
{
    int c = blockIdx.x, t = threadIdx.x;
    const int p = wpack(c, t);
    w1b[p] = f2bf(pre_w[c * 256 + t]);
    w2b[p] = f2bf(pw_w[c * 256 + t]);
    w3b[p] = f2bf(post_w[c * 256 + t]);
    if (t < 128) {
        float val = 0.f;
        int dy = -1, dx = 0;
        if (t < 45) { dy = t / 9; dx = t % 9; }
        else if (t >= 64 && t < 100) { int i = t - 64; dy = 5 + i / 9; dx = i % 9; }
        if (dy >= 0) {
            val = w9d[c * 81 + dy * 9 + dx];
            if (dy >= 1 && dy <= 7 && dx >= 1 && dx <= 7) val += w7d[c * 49 + (dy - 1) * 7 + (dx - 1)];
            if (dy >= 2 && dy <= 6 && dx >= 2 && dx <= 6) val += w5d[c * 25 + (dy - 2) * 5 + (dx - 2)];
            if (dy >= 3 && dy <= 5 && dx >= 3 && dx <= 5) val += w3d[c * 9 + (dy - 3) * 3 + (dx - 3)];
            if (dy == 4 && dx == 4) val += 1.0f;  // identity branch
        }
        WcP[c * 128 + t] = val;
    }
    if (t == 128) { float s = g1[c] * rsqrtf(v1[c] + 1e-5f); sc1[c] = s; sh1[c] = b1[c] - m1[c] * s; }
    if (t == 129) { float s = g2[c] * rsqrtf(v2[c] + 1e-5f); sc2[c] = s; sh2[c] = b2[c] - m2[c] * s; }
    if (t == 130) { float s = g3[c] * rsqrtf(v3[c] + 1e-5f); sc3[c] = s; sh3[c] = b3[c] - m3[c] * s; }
    if (t == 131) biasc[c] = b3d[c] + b5d[c] + b7d[c] + b9d[c];
}

// ---------------------------------------------------------------------------
// LDS-staged MFMA 1x1 conv(s). Each block processes TWO consecutive TILE-px
// tiles: tile1's global loads are issued into registers BEFORE tile0's GEMM,
// so HBM requests stay in flight under compute (T14 issue-early/write-late;
// R4 post-mortem: phase serialization = zero in-flight bytes during GEMM was
// the latency bottleneck, not occupancy).
// MODE 0: in fp32 NCHW -> GEMM(wA)+bnA+relu -> bf16 NCHW       (conv1)
// MODE 1: in bf16 NCHW -> GEMM(wA)+bnA+relu -> t in LDS ->
//         GEMM(wB)+bnB+relu -> fp32 NCHW                       (conv2+conv3)
// launch_bounds(256,2): grid 512 = exactly 2 blocks/CU; reg cap ~256 so the
// 64-reg prefetch + acc + An never spills.
template <int MODE>
__global__ __launch_bounds__(256, 2) void conv_tile(
    const void* __restrict__ inp,
    const ushort_t* __restrict__ wA, const float* __restrict__ scA, const float* __restrict__ shA,
    const ushort_t* __restrict__ wB, const float* __restrict__ scB, const float* __restrict__ shB,
    void* __restrict__ outp)
{
    __shared__ __align__(16) ushort_t Bs[TILE * LSTR];   // 33.8 KB
    const int tid = threadIdx.x;
    unsigned int* Bsd = (unsigned int*)Bs;
    const int c2 = tid & 127, ph = tid >> 7, px0 = ph * (TILE / 2);
    const int wave = tid >> 6, lane = tid & 63, quad = lane >> 4, L = lane & 15;
    const int coutw = wave * 64;

    floatx4 acc[4][NT];

    // GEMM over K=256 (8 chunks of 32): A from global in fragment-packed order
    // (1KB contiguous per wave-fragment, L2-hot, prefetched one chunk ahead),
    // B from LDS. setprio around the MFMA cluster.
    auto run_gemm = [&](const ushort_t* W) {
#pragma unroll
        for (int mt = 0; mt < 4; mt++)
#pragma unroll
            for (int nt = 0; nt < NT; nt++) acc[mt][nt] = (floatx4){0.f, 0.f, 0.f, 0.f};
        const ushort_t* Ab = W + (size_t)wave * 16384 + (size_t)lane * 8;
        short8 Ac[4], An[4];
#pragma unroll
        for (int mt = 0; mt < 4; mt++) Ac[mt] = *(const short8*)(Ab + mt * 512);
#pragma unroll
        for (int kt = 0; kt < 8; kt++) {
            if (kt < 7) {
#pragma unroll
                for (int mt = 0; mt < 4; mt++)
                    An[mt] = *(const short8*)(Ab + ((kt + 1) * 4 + mt) * 512);
            }
            short8 Bf[NT];
#pragma unroll
            for (int nt = 0; nt < NT; nt++)
                Bf[nt] = *(const short8*)&Bs[(nt * 16 + L) * LSTR + kt * 32 + quad * 8];
            __builtin_amdgcn_s_setprio(1);
#pragma unroll
            for (int mt = 0; mt < 4; mt++)
#pragma unroll
                for (int nt = 0; nt < NT; nt++)
                    acc[mt][nt] = __builtin_amdgcn_mfma_f32_16x16x32_bf16(
                        Ac[mt], Bf[nt], acc[mt][nt], 0, 0, 0);
            __builtin_amdgcn_s_setprio(0);
            if (kt < 7) {
#pragma unroll
                for (int mt = 0; mt < 4; mt++) Ac[mt] = An[mt];
            }
        }
    };

    // process the tile currently staged in Bs (P0 = its pixel base)
    auto process = [&](int P0) {
        const int b = P0 >> 12, hw0 = P0 & 4095;
        run_gemm(wA);
        if (MODE == 0) {
            // epilogue: bnA + relu -> bf16 NCHW
            ushort_t* outb = (ushort_t*)outp + (size_t)b * BPL + hw0;
#pragma unroll
            for (int mt = 0; mt < 4; mt++) {
#pragma unroll
                for (int r = 0; r < 4; r++) {
                    const int cout = coutw + mt * 16 + quad * 4 + r;
                    const float s = scA[cout], h0 = shA[cout];
#pragma unroll
                    for (int nt = 0; nt < NT; nt++)
                        outb[(size_t)cout * HW + nt * 16 + L] =
                            f2bf(fmaxf(fmaf(acc[mt][nt][r], s, h0), 0.f));
                }
            }
        } else {
            // t = relu(bnA(.)) -> back into Bs (in-place; tile fully consumed)
            __syncthreads();
#pragma unroll
            for (int mt = 0; mt < 4; mt++) {
                const int cout0 = coutw + mt * 16 + quad * 4;
                float sc4[4], sh4[4];
#pragma unroll
                for (int r = 0; r < 4; r++) { sc4[r] = scA[cout0 + r]; sh4[r] = shA[cout0 + r]; }
#pragma unroll
                for (int nt = 0; nt < NT; nt++) {
                    const int px = nt * 16 + L;
                    ushort4 pk;
                    pk.x = f2bf(fmaxf(fmaf(acc[mt][nt][0], sc4[0], sh4[0]), 0.f));
                    pk.y = f2bf(fmaxf(fmaf(acc[mt][nt][1], sc4[1], sh4[1]), 0.f));
                    pk.z = f2bf(fmaxf(fmaf(acc[mt][nt][2], sc4[2], sh4[2]), 0.f));
                    pk.w = f2bf(fmaxf(fmaf(acc[mt][nt][3], sc4[3], sh4[3]), 0.f));
                    *(ushort4*)&Bs[px * LSTR + cout0] = pk;
                }
            }
            __syncthreads();
            run_gemm(wB);
            // epilogue: bnB + relu -> fp32 NCHW
            float* outb = (float*)outp + (size_t)b * BPL + hw0;
#pragma unroll
            for (int mt = 0; mt < 4; mt++) {
#pragma unroll
                for (int r = 0; r < 4; r++) {
                    const int cout = coutw + mt * 16 + quad * 4 + r;
                    const float s = scB[cout], h0 = shB[cout];
#pragma unroll
                    for (int nt = 0; nt < NT; nt++)
                        outb[(size_t)cout * HW + nt * 16 + L] =
                            fmaxf(fmaf(acc[mt][nt][r], s, h0), 0.f);
                }
            }
        }
    };

    const int P0 = blockIdx.x * (2 * TILE);   // 2 consecutive tiles, same batch
    const int P1 = P0 + TILE;

    // ---- stage tile0 directly [256 ch][TILE px] -> Bs[px][ch]
    {
        const int b = P0 >> 12, hw0 = P0 & 4095;
        if (MODE == 0) {
            const float* s0 = (const float*)inp + (size_t)b * BPL + (size_t)(2 * c2) * HW + hw0 + px0;
            const float* s1 = s0 + HW;
#pragma unroll
            for (int i = 0; i < TILE / 8; i++) {
                float4 v0 = *(const float4*)(s0 + 4 * i);
                float4 v1 = *(const float4*)(s1 + 4 * i);
                const int px = px0 + 4 * i;
                Bsd[(px + 0) * (LSTR / 2) + c2] = (unsigned)f2bf(v0.x) | ((unsigned)f2bf(v1.x) << 16);
                Bsd[(px + 1) * (LSTR / 2) + c2] = (unsigned)f2bf(v0.y) | ((unsigned)f2bf(v1.y) << 16);
                Bsd[(px + 2) * (LSTR / 2) + c2] = (unsigned)f2bf(v0.z) | ((unsigned)f2bf(v1.z) << 16);
                Bsd[(px + 3) * (LSTR / 2) + c2] = (unsigned)f2bf(v0.w) | ((unsigned)f2bf(v1.w) << 16);
            }
        } else {
            const ushort_t* s0 = (const ushort_t*)inp + (size_t)b * BPL + (size_t)(2 * c2) * HW + hw0 + px0;
            const ushort_t* s1 = s0 + HW;
#pragma unroll
            for (int i = 0; i < TILE / 16; i++) {
                union { uint4 v; ushort_t u[8]; } r0, r1;
                r0.v = *(const uint4*)(s0 + 8 * i);
                r1.v = *(const uint4*)(s1 + 8 * i);
                const int px = px0 + 8 * i;
#pragma unroll
                for (int j = 0; j < 8; j++)
                    Bsd[(px + j) * (LSTR / 2) + c2] = (unsigned)r0.u[j] | ((unsigned)r1.u[j] << 16);
            }
        }
    }
    __syncthreads();

    // ---- issue tile1's global loads NOW (they stay in flight under tile0's
    //      GEMMs; consumed only after the post-process barrier)
    float4 pa[8], pb[8];   // MODE0 (fp32 in)
    uint4  qa[4], qb[4];   // MODE1 (bf16 in)
    {
        const int b = P1 >> 12, hw0 = P1 & 4095;
        if (MODE == 0) {
            const float* s0 = (const float*)inp + (size_t)b * BPL + (size_t)(2 * c2) * HW + hw0 + px0;
            const float* s1 = s0 + HW;
#pragma unroll
            for (int i = 0; i < 8; i++) {
                pa[i] = *(const float4*)(s0 + 4 * i);
                pb[i] = *(const float4*)(s1 + 4 * i);
            }
        } else {
            const ushort_t* s0 = (const ushort_t*)inp + (size_t)b * BPL + (size_t)(2 * c2) * HW + hw0 + px0;
            const ushort_t* s1 = s0 + HW;
#pragma unroll
            for (int i = 0; i < 4; i++) {
                qa[i] = *(const uint4*)(s0 + 8 * i);
                qb[i] = *(const uint4*)(s1 + 8 * i);
            }
        }
    }

    process(P0);

    __syncthreads();          // all waves done reading Bs (tile0)

    // ---- write tile1 from regs (loads landed during tile0's compute)
    if (MODE == 0) {
#pragma unroll
        for (int i = 0; i < 8; i++) {
            const int px = px0 + 4 * i;
            Bsd[(px + 0) * (LSTR / 2) + c2] = (unsigned)f2bf(pa[i].x) | ((unsigned)f2bf(pb[i].x) << 16);
            Bsd[(px + 1) * (LSTR / 2) + c2] = (unsigned)f2bf(pa[i].y) | ((unsigned)f2bf(pb[i].y) << 16);
            Bsd[(px + 2) * (LSTR / 2) + c2] = (unsigned)f2bf(pa[i].z) | ((unsigned)f2bf(pb[i].z) << 16);
            Bsd[(px + 3) * (LSTR / 2) + c2] = (unsigned)f2bf(pa[i].w) | ((unsigned)f2bf(pb[i].w) << 16);
        }
    } else {
#pragma unroll
        for (int i = 0; i < 4; i++) {
            union { uint4 v; ushort_t u[8]; } r0, r1;
            r0.v = qa[i]; r1.v = qb[i];
            const int px = px0 + 8 * i;
#pragma unroll
            for (int j = 0; j < 8; j++)
                Bsd[(px + j) * (LSTR / 2) + c2] = (unsigned)r0.u[j] | ((unsigned)r1.u[j] << 16);
        }
    }
    __syncthreads();

    process(P1);
}

// ---------------------------------------------------------------------------
// Combined 9x9 depthwise (+identity, +summed bias), bf16 NCHW in/out.
// Each block processes TWO (b,c) planes with double-buffered bf16 LDS tiles:
// plane1's 32B/thread global loads are issued before plane0's long FIR
// compute (T14), so HBM latency hides under VALU work.
// Conflict-free geometry from R2 (raw bf16 tile, b64 reads) unchanged.
__global__ __launch_bounds__(256, 4) void dw_kernel(
    const ushort_t* __restrict__ h, const float* __restrict__ WcP,
    const float* __restrict__ biasc, ushort_t* __restrict__ out)
{
    const int bcp0 = blockIdx.x * 2;
    __shared__ __align__(16) ushort_t tA[72 * DSTR], tB[72 * DSTR];  // 2x11.8 KB
    const int tid = threadIdx.x;

    // zero halos of BOTH buffers: full rows 0..3 & 68..71 (cols 4..75),
    // interior rows' cols 4..7 and 72..75. All 8B-aligned uint2 stores.
    for (int f = tid; f < 544; f += 256) {
        const int g = (f >= 272) ? f - 272 : f;
        ushort_t* T = (f >= 272) ? tB : tA;
        int row, col;
        if (g < 144) { int rr = g / 18; row = (rr < 4) ? rr : rr + 64; col = 4 + (g % 18) * 4; }
        else { int g2 = g - 144; row = 4 + (g2 >> 1); col = (g2 & 1) ? 72 : 4; }
        *(uint2*)&T[row * DSTR + col] = make_uint2(0u, 0u);
    }

    const int r = tid >> 2, q = tid & 3;
    // stage plane0 -> tA (thread = 32 contiguous bytes of row r; wave = 2KB)
    {
        const ushort_t* src = h + (size_t)bcp0 * HW + r * 64 + q * 16;
        uint4 a = *(const uint4*)src;
        uint4 b = *(const uint4*)(src + 8);
        ushort_t* drow = &tA[(r + 4) * DSTR + 8 + q * 16];
        *(uint2*)(drow + 0)  = make_uint2(a.x, a.y);
        *(uint2*)(drow + 4)  = make_uint2(a.z, a.w);
        *(uint2*)(drow + 8)  = make_uint2(b.x, b.y);
        *(uint2*)(drow + 12) = make_uint2(b.z, b.w);
    }
    __syncthreads();

    // issue plane1's loads NOW (in flight under plane0's FIR compute)
    uint4 p1a, p1b;
    {
        const ushort_t* src = h + (size_t)(bcp0 + 1) * HW + r * 64 + q * 16;
        p1a = *(const uint4*)src;
        p1b = *(const uint4*)(src + 8);
    }

    const int tx = tid & 15, ty = tid >> 4;
    const int x0 = tx * 4, y0 = ty * 4;

    auto compute_store = [&](const ushort_t* tile, int bcp) {
        const int c = bcp & 255;
        const size_t plane = (size_t)bcp * HW;
        float acc[4][4];
#pragma unroll
        for (int i = 0; i < 4; i++)
#pragma unroll
            for (int j = 0; j < 4; j++) acc[i][j] = 0.f;

        const float* wp = WcP + c * 128;
        float wr[48];

        // window row loader: 12 bf16 from tile cols x0+4..x0+15 (3x b64 + unpack)
        auto ldrow = [&](int r6, float* win) {
            const ushort_t* rp = &tile[(y0 + r6) * DSTR + x0 + 4];
            uint2 a = *(const uint2*)rp;
            uint2 b = *(const uint2*)(rp + 4);
            uint2 c2 = *(const uint2*)(rp + 8);
            up2(a.x, win + 0);  up2(a.y, win + 2);
            up2(b.x, win + 4);  up2(b.y, win + 6);
            up2(c2.x, win + 8); up2(c2.y, win + 10);
        };

        // chunk A: dy 0..4 (45 weights), rows y0+0..7
#pragma unroll
        for (int i = 0; i < 12; i++) *(float4*)&wr[4 * i] = *(const float4*)(wp + 4 * i);
#pragma unroll
        for (int r6 = 0; r6 < 8; r6++) {
            float win[12];
            ldrow(r6, win);
#pragma unroll
            for (int yy = 0; yy < 4; yy++) {
                const int d = r6 - yy;
                if (d >= 0 && d <= 4) {
#pragma unroll
                    for (int t = 0; t < 9; t++)
#pragma unroll
                        for (int j = 0; j < 4; j++)
                            acc[yy][j] = fmaf(wr[d * 9 + t], win[j + t], acc[yy][j]);
                }
            }
        }
        // chunk B: dy 5..8 (36 weights), rows y0+5..11
#pragma unroll
        for (int i = 0; i < 9; i++) *(float4*)&wr[4 * i] = *(const float4*)(wp + 64 + 4 * i);
#pragma unroll
        for (int r6 = 5; r6 < 12; r6++) {
            float win[12];
            ldrow(r6, win);
#pragma unroll
            for (int yy = 0; yy < 4; yy++) {
                const int d = r6 - yy;
                if (d >= 5 && d <= 8) {
#pragma unroll
                    for (int t = 0; t < 9; t++)
#pragma unroll
                        for (int j = 0; j < 4; j++)
                            acc[yy][j] = fmaf(wr[(d - 5) * 9 + t], win[j + t], acc[yy][j]);
                }
            }
        }

        const float bb = biasc[c];
#pragma unroll
        for (int yy = 0; yy < 4; yy++) {
            ushort4 o;
            o.x = f2bf(acc[yy][0] + bb);
            o.y = f2bf(acc[yy][1] + bb);
            o.z = f2bf(acc[yy][2] + bb);
            o.w = f2bf(acc[yy][3] + bb);
            *(ushort4*)&out[plane + (size_t)(y0 + yy) * 64 + x0] = o;
        }
    };

    compute_store(tA, bcp0);

    // write plane1 -> tB (loads landed during plane0 compute)
    {
        ushort_t* drow = &tB[(r + 4) * DSTR + 8 + q * 16];
        *(uint2*)(drow + 0)  = make_uint2(p1a.x, p1a.y);
        *(uint2*)(drow + 4)  = make_uint2(p1a.z, p1a.w);
        *(uint2*)(drow + 8)  = make_uint2(p1b.x, p1b.y);
        *(uint2*)(drow + 12) = make_uint2(p1b.z, p1b.w);
    }
    __syncthreads();

    compute_store(tB, bcp0 + 1);
}

// ---------------------------------------------------------------------------
extern "C" void kernel_launch(void* const* d_in, const int* in_sizes, int n_in,
                              void* d_out, int out_size, void* d_ws, size_t ws_size,
                              hipStream_t stream) {
    const float* x     = (const float*)d_in[0];
    const float* pre_w = (const float*)d_in[1];
    const float* bn1g  = (const float*)d_in[2];
    const float* bn1b  = (const float*)d_in[3];
    const float* bn1m  = (const float*)d_in[4];
    const float* bn1v  = (const float*)d_in[5];
    const float* dw3w  = (const float*)d_in[6];
    const float* dw3b  = (const float*)d_in[7];
    const float* dw5w  = (const float*)d_in[8];
    const float* dw5b  = (const float*)d_in[9];
    const float* dw7w  = (const float*)d_in[10];
    const float* dw7b  = (const float*)d_in[11];
    const float* dw9w  = (const float*)d_in[12];
    const float* dw9b  = (const float*)d_in[13];
    const float* pww   = (const float*)d_in[14];
    const float* bn2g  = (const float*)d_in[15];
    const float* bn2b  = (const float*)d_in[16];
    const float* bn2m  = (const float*)d_in[17];
    const float* bn2v  = (const float*)d_in[18];
    const float* postw = (const float*)d_in[19];
    const float* bn3g  = (const float*)d_in[20];
    const float* bn3b  = (const float*)d_in[21];
    const float* bn3m  = (const float*)d_in[22];
    const float* bn3v  = (const float*)d_in[23];

    // Buffers:
    //   h (bf16, 32 MiB)  -> d_out storage (dead before final fp32 write)
    //   s (bf16, 32 MiB)  -> ws[0:32Mi]
    //   aux               -> ws + 33 MiB
    char* wsb = (char*)d_ws;
    ushort_t* sbuf = (ushort_t*)wsb;
    ushort_t* hbuf = (ushort_t*)d_out;
    char* aux = wsb + (size_t)33 * 1024 * 1024;
    ushort_t* w1b = (ushort_t*)aux;
    ushort_t* w2b = w1b + 65536;
    ushort_t* w3b = w2b + 65536;
    float* WcP   = (float*)(w3b + 65536);      // 256*128 fp32
    float* biasc = WcP + 256 * 128;
    float* sc1 = biasc + 256;  float* sh1 = sc1 + 256;
    float* sc2 = sh1 + 256;    float* sh2 = sc2 + 256;
    float* sc3 = sh2 + 256;    float* sh3 = sc3 + 256;

    prep_kernel<<<256, 256, 0, stream>>>(
        pre_w, pww, postw,
        bn1g, bn1b, bn1m, bn1v, bn2g, bn2b, bn2m, bn2v, bn3g, bn3b, bn3m, bn3v,
        dw3w, dw3b, dw5w, dw5b, dw7w, dw7b, dw9w, dw9b,
        w1b, w2b, w3b, WcP, biasc, sc1, sh1, sc2, sh2, sc3, sh3);

    const int nconv = (16 * HW) / (2 * TILE);   // 512 blocks, 2 tiles each
    // conv1: x fp32 -> h bf16 NCHW (in d_out storage)
    conv_tile<0><<<nconv, 256, 0, stream>>>(x, w1b, sc1, sh1,
                                            nullptr, nullptr, nullptr, hbuf);
    // dw: h -> s bf16 NCHW (in ws); 2 planes per block
    dw_kernel<<<8 * CCH, 256, 0, stream>>>(hbuf, WcP, biasc, sbuf);
    // conv2+conv3 fused: s -> out fp32 NCHW (d_out; h dead)
    conv_tile<1><<<nconv, 256, 0, stream>>>(sbuf, w2b, sc2, sh2,
                                            w3b, sc3, sh3, (float*)d_out);
}

// Round 6
// 228.529 us; speedup vs baseline: 1.3016x; 1.3016x over previous
//
#include <hip/hip_runtime.h>
#include <stdint.h>

#define HW 4096
#define CCH 256
#define BPL (CCH * HW)          // per-batch plane elems
#define LSTR 264                // LDS Bs row stride in shorts (256+8 pad; 528B = 16B-aligned)
#define TILE 64                 // conv px-tile (best measured: R3 -> conv0 40.5, conv1 <40.4)
#define NT 4                    // n-tiles per wave (TILE/16)
#define DSTR 84                 // dw bf16 tile row stride in shorts (168B): quarter-wave b64
                                //  reads span one contiguous 128B wrap -> conflict-free.

typedef __attribute__((ext_vector_type(8))) short short8;
typedef __attribute__((ext_vector_type(4))) float floatx4;
typedef unsigned short ushort_t;

__device__ inline ushort_t f2bf(float f) {
    union { float f; unsigned int u; } v; v.f = f;
    unsigned int r = v.u + 0x7FFFu + ((v.u >> 16) & 1u);   // RNE
    return (ushort_t)(r >> 16);
}
// unpack a dword holding 2 bf16 (little-endian: low short = lower col) to 2 floats
__device__ inline void up2(unsigned int d, float* w) {
    union { unsigned int u; float f; } lo, hi;
    lo.u = d << 16; hi.u = d & 0xffff0000u;
    w[0] = lo.f; w[1] = hi.f;
}

// MFMA A-fragment packed weight layout: for 16x16x32 bf16, lane (quad*16+L) of
// wave w holds A[row=cout][k] with cout = w*64 + mt*16 + L, k = kt*32 + quad*8 + e.
// Each wave fragment load = 64 lanes x 16B CONTIGUOUS (1KB). [worth ~14us, R1]
__device__ inline int wpack(int c, int t) {
    const int w  = c >> 6, mt = (c >> 4) & 3, L = c & 15;
    const int kt = t >> 5, quad = (t >> 3) & 3, e = t & 7;
    return ((((w * 8 + kt) * 4 + mt) * 64 + quad * 16 + L) * 8 + e);
}

// ---------------------------------------------------------------------------
// prep: weights->bf16 (fragment-packed), combined dw 9x9 (chunked layout),
// folded BN params. WcP[c][128]: slots 0..44 = dy 0..4 (dy*9+dx), 64..99 = dy 5..8.
__global__ void prep_kernel(
    const float* __restrict__ pre_w, const float* __restrict__ pw_w, const float* __restrict__ post_w,
    const float* __restrict__ g1, const float* __restrict__ b1, const float* __restrict__ m1, const float* __restrict__ v1,
    const float* __restrict__ g2, const float* __restrict__ b2, const float* __restrict__ m2, const float* __restrict__ v2,
    const float* __restrict__ g3, const float* __restrict__ b3, const float* __restrict__ m3, const float* __restrict__ v3,
    const float* __restrict__ w3d, const float* __restrict__ b3d,
    const float* __restrict__ w5d, const float* __restrict__ b5d,
    const float* __restrict__ w7d, const float* __restrict__ b7d,
    const float* __restrict__ w9d, const float* __restrict__ b9d,
    ushort_t* __restrict__ w1b, ushort_t* __restrict__ w2b, ushort_t* __restrict__ w3b,
    float* __restrict__ WcP, float* __restrict__ biasc,
    float* __restrict__ sc1, float* __restrict__ sh1,
    float* __restrict__ sc2, float* __restrict__ sh2,
    float* __restrict__ sc3, float* __restrict__ sh3)
{
    int c = blockIdx.x, t = threadIdx.x;
    const int p = wpack(c, t);
    w1b[p] = f2bf(pre_w[c * 256 + t]);
    w2b[p] = f2bf(pw_w[c * 256 + t]);
    w3b[p] = f2bf(post_w[c * 256 + t]);
    if (t < 128) {
        float val = 0.f;
        int dy = -1, dx = 0;
        if (t < 45) { dy = t / 9; dx = t % 9; }
        else if (t >= 64 && t < 100) { int i = t - 64; dy = 5 + i / 9; dx = i % 9; }
        if (dy >= 0) {
            val = w9d[c * 81 + dy * 9 + dx];
            if (dy >= 1 && dy <= 7 && dx >= 1 && dx <= 7) val += w7d[c * 49 + (dy - 1) * 7 + (dx - 1)];
            if (dy >= 2 && dy <= 6 && dx >= 2 && dx <= 6) val += w5d[c * 25 + (dy - 2) * 5 + (dx - 2)];
            if (dy >= 3 && dy <= 5 && dx >= 3 && dx <= 5) val += w3d[c * 9 + (dy - 3) * 3 + (dx - 3)];
            if (dy == 4 && dx == 4) val += 1.0f;  // identity branch
        }
        WcP[c * 128 + t] = val;
    }
    if (t == 128) { float s = g1[c] * rsqrtf(v1[c] + 1e-5f); sc1[c] = s; sh1[c] = b1[c] - m1[c] * s; }
    if (t == 129) { float s = g2[c] * rsqrtf(v2[c] + 1e-5f); sc2[c] = s; sh2[c] = b2[c] - m2[c] * s; }
    if (t == 130) { float s = g3[c] * rsqrtf(v3[c] + 1e-5f); sc3[c] = s; sh3[c] = b3[c] - m3[c] * s; }
    if (t == 131) biasc[c] = b3d[c] + b5d[c] + b7d[c] + b9d[c];
}

// ---------------------------------------------------------------------------
// LDS-staged MFMA 1x1 conv(s) on a TILE-px tile, all 256 cout, K=256.
// Staging transposes the NCHW input tile into Bs[px][ch] bf16 (fuses the
// transpose kernels). Wave w computes cout 64w..64w+63 (4 m-tiles x NT n-tiles).
// MODE 0: in fp32 NCHW -> GEMM(wA)+bnA+relu -> bf16 NCHW       (conv1)
// MODE 1: in bf16 NCHW -> GEMM(wA)+bnA+relu -> t in LDS ->
//         GEMM(wB)+bnB+relu -> fp32 NCHW (non-temporal)        (conv2+conv3)
// [R3 config — best measured per-kernel. R4 (TILE32, no An) and R5 (2-tile
//  T14 restructure) both regressed; reverted.]
template <int MODE>
__global__ __launch_bounds__(256, 4) void conv_tile(
    const void* __restrict__ inp,
    const ushort_t* __restrict__ wA, const float* __restrict__ scA, const float* __restrict__ shA,
    const ushort_t* __restrict__ wB, const float* __restrict__ scB, const float* __restrict__ shB,
    void* __restrict__ outp)
{
    __shared__ __align__(16) ushort_t Bs[TILE * LSTR];   // 33.8 KB
    const int tid = threadIdx.x;
    const int P0 = blockIdx.x * TILE;         // global pixel base (never crosses batch)
    const int b = P0 >> 12, hw0 = P0 & 4095;
    unsigned int* Bsd = (unsigned int*)Bs;

    // ---- stage input tile [256 ch][TILE px] -> Bs[px][ch] (ch-pairs packed as dwords)
    // thread t: ch-pair c2 = t&127, px half ph = t>>7 (TILE/2 px each)
    {
        const int c2 = tid & 127, ph = tid >> 7, px0 = ph * (TILE / 2);
        if (MODE == 0) {
            const float* s0 = (const float*)inp + (size_t)b * BPL + (size_t)(2 * c2) * HW + hw0 + px0;
            const float* s1 = s0 + HW;
#pragma unroll
            for (int i = 0; i < TILE / 8; i++) {
                float4 v0 = *(const float4*)(s0 + 4 * i);
                float4 v1 = *(const float4*)(s1 + 4 * i);
                const int px = px0 + 4 * i;
                Bsd[(px + 0) * (LSTR / 2) + c2] = (unsigned)f2bf(v0.x) | ((unsigned)f2bf(v1.x) << 16);
                Bsd[(px + 1) * (LSTR / 2) + c2] = (unsigned)f2bf(v0.y) | ((unsigned)f2bf(v1.y) << 16);
                Bsd[(px + 2) * (LSTR / 2) + c2] = (unsigned)f2bf(v0.z) | ((unsigned)f2bf(v1.z) << 16);
                Bsd[(px + 3) * (LSTR / 2) + c2] = (unsigned)f2bf(v0.w) | ((unsigned)f2bf(v1.w) << 16);
            }
        } else {
            const ushort_t* s0 = (const ushort_t*)inp + (size_t)b * BPL + (size_t)(2 * c2) * HW + hw0 + px0;
            const ushort_t* s1 = s0 + HW;
#pragma unroll
            for (int i = 0; i < TILE / 16; i++) {
                union { uint4 v; ushort_t u[8]; } r0, r1;
                r0.v = *(const uint4*)(s0 + 8 * i);
                r1.v = *(const uint4*)(s1 + 8 * i);
                const int px = px0 + 8 * i;
#pragma unroll
                for (int j = 0; j < 8; j++)
                    Bsd[(px + j) * (LSTR / 2) + c2] = (unsigned)r0.u[j] | ((unsigned)r1.u[j] << 16);
            }
        }
    }
    __syncthreads();

    const int wave = tid >> 6, lane = tid & 63, quad = lane >> 4, L = lane & 15;
    const int coutw = wave * 64;

    floatx4 acc[4][NT];

    // GEMM over K=256 (8 chunks of 32): A from global in fragment-packed order
    // (1KB contiguous per wave-fragment, L2-hot, prefetched one chunk ahead),
    // B from LDS. setprio around the MFMA cluster.
    auto run_gemm = [&](const ushort_t* W) {
#pragma unroll
        for (int mt = 0; mt < 4; mt++)
#pragma unroll
            for (int nt = 0; nt < NT; nt++) acc[mt][nt] = (floatx4){0.f, 0.f, 0.f, 0.f};
        const ushort_t* Ab = W + (size_t)wave * 16384 + (size_t)lane * 8;
        short8 Ac[4], An[4];
#pragma unroll
        for (int mt = 0; mt < 4; mt++) Ac[mt] = *(const short8*)(Ab + mt * 512);
#pragma unroll
        for (int kt = 0; kt < 8; kt++) {
            if (kt < 7) {
#pragma unroll
                for (int mt = 0; mt < 4; mt++)
                    An[mt] = *(const short8*)(Ab + ((kt + 1) * 4 + mt) * 512);
            }
            short8 Bf[NT];
#pragma unroll
            for (int nt = 0; nt < NT; nt++)
                Bf[nt] = *(const short8*)&Bs[(nt * 16 + L) * LSTR + kt * 32 + quad * 8];
            __builtin_amdgcn_s_setprio(1);
#pragma unroll
            for (int mt = 0; mt < 4; mt++)
#pragma unroll
                for (int nt = 0; nt < NT; nt++)
                    acc[mt][nt] = __builtin_amdgcn_mfma_f32_16x16x32_bf16(
                        Ac[mt], Bf[nt], acc[mt][nt], 0, 0, 0);
            __builtin_amdgcn_s_setprio(0);
            if (kt < 7) {
#pragma unroll
                for (int mt = 0; mt < 4; mt++) Ac[mt] = An[mt];
            }
        }
    };

    run_gemm(wA);

    if (MODE == 0) {
        // epilogue: bnA + relu -> bf16 NCHW (h is re-read by dw: keep cached stores)
        ushort_t* outb = (ushort_t*)outp + (size_t)b * BPL + hw0;
#pragma unroll
        for (int mt = 0; mt < 4; mt++) {
#pragma unroll
            for (int r = 0; r < 4; r++) {
                const int cout = coutw + mt * 16 + quad * 4 + r;
                const float s = scA[cout], h0 = shA[cout];
#pragma unroll
                for (int nt = 0; nt < NT; nt++)
                    outb[(size_t)cout * HW + nt * 16 + L] =
                        f2bf(fmaxf(fmaf(acc[mt][nt][r], s, h0), 0.f));
            }
        }
    } else {
        // t = relu(bnA(.)) -> back into Bs (in-place; tile fully consumed)
        __syncthreads();
#pragma unroll
        for (int mt = 0; mt < 4; mt++) {
            const int cout0 = coutw + mt * 16 + quad * 4;
            float sc4[4], sh4[4];
#pragma unroll
            for (int r = 0; r < 4; r++) { sc4[r] = scA[cout0 + r]; sh4[r] = shA[cout0 + r]; }
#pragma unroll
            for (int nt = 0; nt < NT; nt++) {
                const int px = nt * 16 + L;
                ushort4 pk;
                pk.x = f2bf(fmaxf(fmaf(acc[mt][nt][0], sc4[0], sh4[0]), 0.f));
                pk.y = f2bf(fmaxf(fmaf(acc[mt][nt][1], sc4[1], sh4[1]), 0.f));
                pk.z = f2bf(fmaxf(fmaf(acc[mt][nt][2], sc4[2], sh4[2]), 0.f));
                pk.w = f2bf(fmaxf(fmaf(acc[mt][nt][3], sc4[3], sh4[3]), 0.f));
                *(ushort4*)&Bs[px * LSTR + cout0] = pk;
            }
        }
        __syncthreads();
        run_gemm(wB);
        // epilogue: bnB + relu -> fp32 NCHW. NON-TEMPORAL: 64MB streamed out,
        // never re-read -> don't evict L2-hot weights / staged tiles.
        float* outb = (float*)outp + (size_t)b * BPL + hw0;
#pragma unroll
        for (int mt = 0; mt < 4; mt++) {
#pragma unroll
            for (int r = 0; r < 4; r++) {
                const int cout = coutw + mt * 16 + quad * 4 + r;
                const float s = scB[cout], h0 = shB[cout];
#pragma unroll
                for (int nt = 0; nt < NT; nt++)
                    __builtin_nontemporal_store(
                        fmaxf(fmaf(acc[mt][nt][r], s, h0), 0.f),
                        &outb[(size_t)cout * HW + nt * 16 + L]);
            }
        }
    }
}

// ---------------------------------------------------------------------------
// Combined 9x9 depthwise (+identity, +summed bias), bf16 NCHW in/out.
// One block per (b,c) plane. Tile stored as RAW bf16 (input is already bf16):
//  - staging is a straight copy (no convert VALU), writes are ds_write_b64
//    with (5r+4q mod 16) bank-pair tiling -> conflict-free
//  - window reads are 3x ds_read_b64/row: a quarter-wave (fixed ty, tx=0..15)
//    spans ONE contiguous 128B wrap -> conflict-free by construction
//  - LDS traffic halves (bf16 vs f32); unpack = shift/and in VALU (+12/row)
// Tile 72 rows x DSTR(84) shorts = 11.8 KB.
// [R5's 2-plane T14 variant regressed badly (47 -> 99us); single-plane kept.]
__global__ __launch_bounds__(256, 3) void dw_kernel(
    const ushort_t* __restrict__ h, const float* __restrict__ WcP,
    const float* __restrict__ biasc, ushort_t* __restrict__ out)
{
    const int bcp = blockIdx.x, c = bcp & 255;
    const size_t plane = (size_t)bcp * HW;
    __shared__ __align__(16) ushort_t tile[72 * DSTR];   // 11.8 KB
    const int tid = threadIdx.x;

    // zero halo: full rows 0..3 & 68..71 (cols 4..75 used), interior rows'
    // left cols 4..7 and right cols 72..75. All 8B-aligned uint2 stores.
    for (int f = tid; f < 272; f += 256) {
        int row, col;
        if (f < 144) { int rr = f / 18; row = (rr < 4) ? rr : rr + 64; col = 4 + (f % 18) * 4; }
        else { int f2 = f - 144; row = 4 + (f2 >> 1); col = (f2 & 1) ? 72 : 4; }
        *(uint2*)&tile[row * DSTR + col] = make_uint2(0u, 0u);
    }
    // interior: thread copies 32 contiguous bytes (16 px) of input row r.
    // Global: consecutive 4 threads cover a full 128B row; wave = 2KB contiguous.
    // Interior pixels live at tile cols 8..71 (left pad keeps stores 8B-aligned).
    {
        const int r = tid >> 2, q = tid & 3;
        const ushort_t* src = h + plane + r * 64 + q * 16;
        uint4 a = *(const uint4*)src;
        uint4 b = *(const uint4*)(src + 8);
        ushort_t* drow = &tile[(r + 4) * DSTR + 8 + q * 16];
        *(uint2*)(drow + 0)  = make_uint2(a.x, a.y);
        *(uint2*)(drow + 4)  = make_uint2(a.z, a.w);
        *(uint2*)(drow + 8)  = make_uint2(b.x, b.y);
        *(uint2*)(drow + 12) = make_uint2(b.z, b.w);
    }
    __syncthreads();

    const int tx = tid & 15, ty = tid >> 4;
    const int x0 = tx * 4, y0 = ty * 4;
    float acc[4][4];
#pragma unroll
    for (int i = 0; i < 4; i++)
#pragma unroll
        for (int j = 0; j < 4; j++) acc[i][j] = 0.f;

    const float* wp = WcP + c * 128;
    float wr[48];

    // window row loader: 12 bf16 from tile cols x0+4 .. x0+15 (3x b64 + unpack)
    auto ldrow = [&](int r6, float* win) {
        const ushort_t* rp = &tile[(y0 + r6) * DSTR + x0 + 4];
        uint2 a = *(const uint2*)rp;
        uint2 b = *(const uint2*)(rp + 4);
        uint2 c2 = *(const uint2*)(rp + 8);
        up2(a.x, win + 0);  up2(a.y, win + 2);
        up2(b.x, win + 4);  up2(b.y, win + 6);
        up2(c2.x, win + 8); up2(c2.y, win + 10);
    };

    // chunk A: dy 0..4 (45 weights), rows y0+0..7
#pragma unroll
    for (int i = 0; i < 12; i++) *(float4*)&wr[4 * i] = *(const float4*)(wp + 4 * i);
#pragma unroll
    for (int r6 = 0; r6 < 8; r6++) {
        float win[12];
        ldrow(r6, win);
#pragma unroll
        for (int yy = 0; yy < 4; yy++) {
            const int d = r6 - yy;
            if (d >= 0 && d <= 4) {
#pragma unroll
                for (int t = 0; t < 9; t++)
#pragma unroll
                    for (int j = 0; j < 4; j++)
                        acc[yy][j] = fmaf(wr[d * 9 + t], win[j + t], acc[yy][j]);
            }
        }
    }
    // chunk B: dy 5..8 (36 weights), rows y0+5..11
#pragma unroll
    for (int i = 0; i < 9; i++) *(float4*)&wr[4 * i] = *(const float4*)(wp + 64 + 4 * i);
#pragma unroll
    for (int r6 = 5; r6 < 12; r6++) {
        float win[12];
        ldrow(r6, win);
#pragma unroll
        for (int yy = 0; yy < 4; yy++) {
            const int d = r6 - yy;
            if (d >= 5 && d <= 8) {
#pragma unroll
                for (int t = 0; t < 9; t++)
#pragma unroll
                    for (int j = 0; j < 4; j++)
                        acc[yy][j] = fmaf(wr[(d - 5) * 9 + t], win[j + t], acc[yy][j]);
            }
        }
    }

    const float bb = biasc[c];
#pragma unroll
    for (int yy = 0; yy < 4; yy++) {
        ushort4 o;
        o.x = f2bf(acc[yy][0] + bb);
        o.y = f2bf(acc[yy][1] + bb);
        o.z = f2bf(acc[yy][2] + bb);
        o.w = f2bf(acc[yy][3] + bb);
        *(ushort4*)&out[plane + (size_t)(y0 + yy) * 64 + x0] = o;
    }
}

// ---------------------------------------------------------------------------
extern "C" void kernel_launch(void* const* d_in, const int* in_sizes, int n_in,
                              void* d_out, int out_size, void* d_ws, size_t ws_size,
                              hipStream_t stream) {
    const float* x     = (const float*)d_in[0];
    const float* pre_w = (const float*)d_in[1];
    const float* bn1g  = (const float*)d_in[2];
    const float* bn1b  = (const float*)d_in[3];
    const float* bn1m  = (const float*)d_in[4];
    const float* bn1v  = (const float*)d_in[5];
    const float* dw3w  = (const float*)d_in[6];
    const float* dw3b  = (const float*)d_in[7];
    const float* dw5w  = (const float*)d_in[8];
    const float* dw5b  = (const float*)d_in[9];
    const float* dw7w  = (const float*)d_in[10];
    const float* dw7b  = (const float*)d_in[11];
    const float* dw9w  = (const float*)d_in[12];
    const float* dw9b  = (const float*)d_in[13];
    const float* pww   = (const float*)d_in[14];
    const float* bn2g  = (const float*)d_in[15];
    const float* bn2b  = (const float*)d_in[16];
    const float* bn2m  = (const float*)d_in[17];
    const float* bn2v  = (const float*)d_in[18];
    const float* postw = (const float*)d_in[19];
    const float* bn3g  = (const float*)d_in[20];
    const float* bn3b  = (const float*)d_in[21];
    const float* bn3m  = (const float*)d_in[22];
    const float* bn3v  = (const float*)d_in[23];

    // Buffers:
    //   h (bf16, 32 MiB)  -> d_out storage (dead before final fp32 write)
    //   s (bf16, 32 MiB)  -> ws[0:32Mi]
    //   aux               -> ws + 33 MiB
    char* wsb = (char*)d_ws;
    ushort_t* sbuf = (ushort_t*)wsb;
    ushort_t* hbuf = (ushort_t*)d_out;
    char* aux = wsb + (size_t)33 * 1024 * 1024;
    ushort_t* w1b = (ushort_t*)aux;
    ushort_t* w2b = w1b + 65536;
    ushort_t* w3b = w2b + 65536;
    float* WcP   = (float*)(w3b + 65536);      // 256*128 fp32
    float* biasc = WcP + 256 * 128;
    float* sc1 = biasc + 256;  float* sh1 = sc1 + 256;
    float* sc2 = sh1 + 256;    float* sh2 = sc2 + 256;
    float* sc3 = sh2 + 256;    float* sh3 = sc3 + 256;

    prep_kernel<<<256, 256, 0, stream>>>(
        pre_w, pww, postw,
        bn1g, bn1b, bn1m, bn1v, bn2g, bn2b, bn2m, bn2v, bn3g, bn3b, bn3m, bn3v,
        dw3w, dw3b, dw5w, dw5b, dw7w, dw7b, dw9w, dw9b,
        w1b, w2b, w3b, WcP, biasc, sc1, sh1, sc2, sh2, sc3, sh3);

    const int nconv = (16 * HW) / TILE;   // 1024 blocks
    // conv1: x fp32 -> h bf16 NCHW (in d_out storage)
    conv_tile<0><<<nconv, 256, 0, stream>>>(x, w1b, sc1, sh1,
                                            nullptr, nullptr, nullptr, hbuf);
    // dw: h -> s bf16 NCHW (in ws)
    dw_kernel<<<16 * CCH, 256, 0, stream>>>(hbuf, WcP, biasc, sbuf);
    // conv2+conv3 fused: s -> out fp32 NCHW (d_out; h dead)
    conv_tile<1><<<nconv, 256, 0, stream>>>(sbuf, w2b, sc2, sh2,
                                            w3b, sc3, sh3, (float*)d_out);
}

// Round 7
// 227.545 us; speedup vs baseline: 1.3072x; 1.0043x over previous
//
#include <hip/hip_runtime.h>
#include <stdint.h>

#define HW 4096
#define CCH 256
#define BPL (CCH * HW)          // per-batch plane elems
#define LSTR 264                // LDS Bs row stride in shorts (256+8 pad; 528B = 16B-aligned)
#define TILE 64                 // conv px-tile (best measured: R3/R6)
#define NT 4                    // n-tiles per wave (TILE/16)
#define DSTR 84                 // dw bf16 tile row stride in shorts (168B): quarter-wave b64
                                //  reads span one contiguous 128B wrap -> conflict-free.

typedef __attribute__((ext_vector_type(8))) short short8;
typedef __attribute__((ext_vector_type(4))) float floatx4;
typedef unsigned short ushort_t;

__device__ inline ushort_t f2bf(float f) {
    union { float f; unsigned int u; } v; v.f = f;
    unsigned int r = v.u + 0x7FFFu + ((v.u >> 16) & 1u);   // RNE
    return (ushort_t)(r >> 16);
}
// unpack a dword holding 2 bf16 (little-endian: low short = lower col) to 2 floats
__device__ inline void up2(unsigned int d, float* w) {
    union { unsigned int u; float f; } lo, hi;
    lo.u = d << 16; hi.u = d & 0xffff0000u;
    w[0] = lo.f; w[1] = hi.f;
}

// MFMA A-fragment packed weight layout: for 16x16x32 bf16, lane (quad*16+L) of
// wave w holds A[row=cout][k] with cout = w*64 + mt*16 + L, k = kt*32 + quad*8 + e.
// Each wave fragment load = 64 lanes x 16B CONTIGUOUS (1KB). [worth ~14us, R1]
__device__ inline int wpack(int c, int t) {
    const int w  = c >> 6, mt = (c >> 4) & 3, L = c & 15;
    const int kt = t >> 5, quad = (t >> 3) & 3, e = t & 7;
    return ((((w * 8 + kt) * 4 + mt) * 64 + quad * 16 + L) * 8 + e);
}

// ---------------------------------------------------------------------------
// prep: weights->bf16 (fragment-packed), combined dw 9x9 (chunked layout),
// folded BN params. WcP[c][128]: slots 0..44 = dy 0..4 (dy*9+dx), 64..99 = dy 5..8.
__global__ void prep_kernel(
    const float* __restrict__ pre_w, const float* __restrict__ pw_w, const float* __restrict__ post_w,
    const float* __restrict__ g1, const float* __restrict__ b1, const float* __restrict__ m1, const float* __restrict__ v1,
    const float* __restrict__ g2, const float* __restrict__ b2, const float* __restrict__ m2, const float* __restrict__ v2,
    const float* __restrict__ g3, const float* __restrict__ b3, const float* __restrict__ m3, const float* __restrict__ v3,
    const float* __restrict__ w3d, const float* __restrict__ b3d,
    const float* __restrict__ w5d, const float* __restrict__ b5d,
    const float* __restrict__ w7d, const float* __restrict__ b7d,
    const float* __restrict__ w9d, const float* __restrict__ b9d,
    ushort_t* __restrict__ w1b, ushort_t* __restrict__ w2b, ushort_t* __restrict__ w3b,
    float* __restrict__ WcP, float* __restrict__ biasc,
    float* __restrict__ sc1, float* __restrict__ sh1,
    float* __restrict__ sc2, float* __restrict__ sh2,
    float* __restrict__ sc3, float* __restrict__ sh3)
{
    int c = blockIdx.x, t = threadIdx.x;
    const int p = wpack(c, t);
    w1b[p] = f2bf(pre_w[c * 256 + t]);
    w2b[p] = f2bf(pw_w[c * 256 + t]);
    w3b[p] = f2bf(post_w[c * 256 + t]);
    if (t < 128) {
        float val = 0.f;
        int dy = -1, dx = 0;
        if (t < 45) { dy = t / 9; dx = t % 9; }
        else if (t >= 64 && t < 100) { int i = t - 64; dy = 5 + i / 9; dx = i % 9; }
        if (dy >= 0) {
            val = w9d[c * 81 + dy * 9 + dx];
            if (dy >= 1 && dy <= 7 && dx >= 1 && dx <= 7) val += w7d[c * 49 + (dy - 1) * 7 + (dx - 1)];
            if (dy >= 2 && dy <= 6 && dx >= 2 && dx <= 6) val += w5d[c * 25 + (dy - 2) * 5 + (dx - 2)];
            if (dy >= 3 && dy <= 5 && dx >= 3 && dx <= 5) val += w3d[c * 9 + (dy - 3) * 3 + (dx - 3)];
            if (dy == 4 && dx == 4) val += 1.0f;  // identity branch
        }
        WcP[c * 128 + t] = val;
    }
    if (t == 128) { float s = g1[c] * rsqrtf(v1[c] + 1e-5f); sc1[c] = s; sh1[c] = b1[c] - m1[c] * s; }
    if (t == 129) { float s = g2[c] * rsqrtf(v2[c] + 1e-5f); sc2[c] = s; sh2[c] = b2[c] - m2[c] * s; }
    if (t == 130) { float s = g3[c] * rsqrtf(v3[c] + 1e-5f); sc3[c] = s; sh3[c] = b3[c] - m3[c] * s; }
    if (t == 131) biasc[c] = b3d[c] + b5d[c] + b7d[c] + b9d[c];
}

// ---------------------------------------------------------------------------
// LDS-staged MFMA 1x1 conv(s) on a TILE-px tile, all 256 cout, K=256.
// Staging transposes the NCHW input tile into Bs[px][ch] bf16.
// R7: staging is two-phase — issue ALL global loads into a register batch
// (no dependent ops between them -> one HBM latency for the whole batch;
// R6's VGPR=64 showed the compiler was serializing ~2-4 loads at a time),
// then convert+write to LDS. Wave w computes cout 64w..64w+63.
// MODE 0: in fp32 NCHW -> GEMM(wA)+bnA+relu -> bf16 NCHW       (conv1)
// MODE 1: in bf16 NCHW -> GEMM(wA)+bnA+relu -> t in LDS ->
//         GEMM(wB)+bnB+relu -> fp32 NCHW (non-temporal)        (conv2+conv3)
template <int MODE>
__global__ __launch_bounds__(256, 4) void conv_tile(
    const void* __restrict__ inp,
    const ushort_t* __restrict__ wA, const float* __restrict__ scA, const float* __restrict__ shA,
    const ushort_t* __restrict__ wB, const float* __restrict__ scB, const float* __restrict__ shB,
    void* __restrict__ outp)
{
    __shared__ __align__(16) ushort_t Bs[TILE * LSTR];   // 33.8 KB
    const int tid = threadIdx.x;
    const int P0 = blockIdx.x * TILE;         // global pixel base (never crosses batch)
    const int b = P0 >> 12, hw0 = P0 & 4095;
    unsigned int* Bsd = (unsigned int*)Bs;

    // ---- stage input tile [256 ch][TILE px] -> Bs[px][ch] (ch-pairs packed as dwords)
    // thread t: ch-pair c2 = t&127, px half ph = t>>7 (TILE/2 px each)
    {
        const int c2 = tid & 127, ph = tid >> 7, px0 = ph * (TILE / 2);
        if (MODE == 0) {
            const float* s0 = (const float*)inp + (size_t)b * BPL + (size_t)(2 * c2) * HW + hw0 + px0;
            const float* s1 = s0 + HW;
            float4 v0[8], v1[8];           // 64 VGPR: all 16 loads in flight at once
#pragma unroll
            for (int i = 0; i < 8; i++) {
                v0[i] = *(const float4*)(s0 + 4 * i);
                v1[i] = *(const float4*)(s1 + 4 * i);
            }
#pragma unroll
            for (int i = 0; i < 8; i++) {
                const int px = px0 + 4 * i;
                Bsd[(px + 0) * (LSTR / 2) + c2] = (unsigned)f2bf(v0[i].x) | ((unsigned)f2bf(v1[i].x) << 16);
                Bsd[(px + 1) * (LSTR / 2) + c2] = (unsigned)f2bf(v0[i].y) | ((unsigned)f2bf(v1[i].y) << 16);
                Bsd[(px + 2) * (LSTR / 2) + c2] = (unsigned)f2bf(v0[i].z) | ((unsigned)f2bf(v1[i].z) << 16);
                Bsd[(px + 3) * (LSTR / 2) + c2] = (unsigned)f2bf(v0[i].w) | ((unsigned)f2bf(v1[i].w) << 16);
            }
        } else {
            const ushort_t* s0 = (const ushort_t*)inp + (size_t)b * BPL + (size_t)(2 * c2) * HW + hw0 + px0;
            const ushort_t* s1 = s0 + HW;
            uint4 q0[4], q1[4];            // 32 VGPR: all 8 loads in flight
#pragma unroll
            for (int i = 0; i < 4; i++) {
                q0[i] = *(const uint4*)(s0 + 8 * i);
                q1[i] = *(const uint4*)(s1 + 8 * i);
            }
#pragma unroll
            for (int i = 0; i < 4; i++) {
                union { uint4 v; ushort_t u[8]; } r0, r1;
                r0.v = q0[i]; r1.v = q1[i];
                const int px = px0 + 8 * i;
#pragma unroll
                for (int j = 0; j < 8; j++)
                    Bsd[(px + j) * (LSTR / 2) + c2] = (unsigned)r0.u[j] | ((unsigned)r1.u[j] << 16);
            }
        }
    }
    __syncthreads();

    const int wave = tid >> 6, lane = tid & 63, quad = lane >> 4, L = lane & 15;
    const int coutw = wave * 64;

    floatx4 acc[4][NT];

    // GEMM over K=256 (8 chunks of 32): A from global in fragment-packed order
    // (1KB contiguous per wave-fragment, L2-hot, prefetched one chunk ahead),
    // B from LDS. setprio around the MFMA cluster.
    auto run_gemm = [&](const ushort_t* W) {
#pragma unroll
        for (int mt = 0; mt < 4; mt++)
#pragma unroll
            for (int nt = 0; nt < NT; nt++) acc[mt][nt] = (floatx4){0.f, 0.f, 0.f, 0.f};
        const ushort_t* Ab = W + (size_t)wave * 16384 + (size_t)lane * 8;
        short8 Ac[4], An[4];
#pragma unroll
        for (int mt = 0; mt < 4; mt++) Ac[mt] = *(const short8*)(Ab + mt * 512);
#pragma unroll
        for (int kt = 0; kt < 8; kt++) {
            if (kt < 7) {
#pragma unroll
                for (int mt = 0; mt < 4; mt++)
                    An[mt] = *(const short8*)(Ab + ((kt + 1) * 4 + mt) * 512);
            }
            short8 Bf[NT];
#pragma unroll
            for (int nt = 0; nt < NT; nt++)
                Bf[nt] = *(const short8*)&Bs[(nt * 16 + L) * LSTR + kt * 32 + quad * 8];
            __builtin_amdgcn_s_setprio(1);
#pragma unroll
            for (int mt = 0; mt < 4; mt++)
#pragma unroll
                for (int nt = 0; nt < NT; nt++)
                    acc[mt][nt] = __builtin_amdgcn_mfma_f32_16x16x32_bf16(
                        Ac[mt], Bf[nt], acc[mt][nt], 0, 0, 0);
            __builtin_amdgcn_s_setprio(0);
            if (kt < 7) {
#pragma unroll
                for (int mt = 0; mt < 4; mt++) Ac[mt] = An[mt];
            }
        }
    };

    run_gemm(wA);

    if (MODE == 0) {
        // epilogue: bnA + relu -> bf16 NCHW (h is re-read by dw: keep cached stores)
        ushort_t* outb = (ushort_t*)outp + (size_t)b * BPL + hw0;
#pragma unroll
        for (int mt = 0; mt < 4; mt++) {
#pragma unroll
            for (int r = 0; r < 4; r++) {
                const int cout = coutw + mt * 16 + quad * 4 + r;
                const float s = scA[cout], h0 = shA[cout];
#pragma unroll
                for (int nt = 0; nt < NT; nt++)
                    outb[(size_t)cout * HW + nt * 16 + L] =
                        f2bf(fmaxf(fmaf(acc[mt][nt][r], s, h0), 0.f));
            }
        }
    } else {
        // t = relu(bnA(.)) -> back into Bs (in-place; tile fully consumed)
        __syncthreads();
#pragma unroll
        for (int mt = 0; mt < 4; mt++) {
            const int cout0 = coutw + mt * 16 + quad * 4;
            float sc4[4], sh4[4];
#pragma unroll
            for (int r = 0; r < 4; r++) { sc4[r] = scA[cout0 + r]; sh4[r] = shA[cout0 + r]; }
#pragma unroll
            for (int nt = 0; nt < NT; nt++) {
                const int px = nt * 16 + L;
                ushort4 pk;
                pk.x = f2bf(fmaxf(fmaf(acc[mt][nt][0], sc4[0], sh4[0]), 0.f));
                pk.y = f2bf(fmaxf(fmaf(acc[mt][nt][1], sc4[1], sh4[1]), 0.f));
                pk.z = f2bf(fmaxf(fmaf(acc[mt][nt][2], sc4[2], sh4[2]), 0.f));
                pk.w = f2bf(fmaxf(fmaf(acc[mt][nt][3], sc4[3], sh4[3]), 0.f));
                *(ushort4*)&Bs[px * LSTR + cout0] = pk;
            }
        }
        __syncthreads();
        run_gemm(wB);
        // epilogue: bnB + relu -> fp32 NCHW. NON-TEMPORAL: 64MB streamed out,
        // never re-read -> don't evict L2-hot weights / staged tiles.
        float* outb = (float*)outp + (size_t)b * BPL + hw0;
#pragma unroll
        for (int mt = 0; mt < 4; mt++) {
#pragma unroll
            for (int r = 0; r < 4; r++) {
                const int cout = coutw + mt * 16 + quad * 4 + r;
                const float s = scB[cout], h0 = shB[cout];
#pragma unroll
                for (int nt = 0; nt < NT; nt++)
                    __builtin_nontemporal_store(
                        fmaxf(fmaf(acc[mt][nt][r], s, h0), 0.f),
                        &outb[(size_t)cout * HW + nt * 16 + L]);
            }
        }
    }
}

// ---------------------------------------------------------------------------
// Combined 9x9 depthwise (+identity, +summed bias), bf16 NCHW in/out.
// One block per (b,c) plane. Tile stored as RAW bf16 (input is already bf16):
//  - interior global loads issued FIRST, halo-zero VALU overlaps their latency,
//    then interior regs written to LDS (issue-early/write-late in miniature)
//  - window reads are 3x ds_read_b64/row: a quarter-wave (fixed ty, tx=0..15)
//    spans ONE contiguous 128B wrap -> conflict-free by construction
//  - LDS traffic halves (bf16 vs f32); unpack = shift/and in VALU (+12/row)
// Tile 72 rows x DSTR(84) shorts = 11.8 KB.
__global__ __launch_bounds__(256, 3) void dw_kernel(
    const ushort_t* __restrict__ h, const float* __restrict__ WcP,
    const float* __restrict__ biasc, ushort_t* __restrict__ out)
{
    const int bcp = blockIdx.x, c = bcp & 255;
    const size_t plane = (size_t)bcp * HW;
    __shared__ __align__(16) ushort_t tile[72 * DSTR];   // 11.8 KB
    const int tid = threadIdx.x;

    // issue interior loads first (32B/thread); halo fill below hides latency
    const int r = tid >> 2, q = tid & 3;
    uint4 ia, ib;
    {
        const ushort_t* src = h + plane + r * 64 + q * 16;
        ia = *(const uint4*)src;
        ib = *(const uint4*)(src + 8);
    }

    // zero halo: full rows 0..3 & 68..71 (cols 4..75 used), interior rows'
    // left cols 4..7 and right cols 72..75. All 8B-aligned uint2 stores.
    for (int f = tid; f < 272; f += 256) {
        int row, col;
        if (f < 144) { int rr = f / 18; row = (rr < 4) ? rr : rr + 64; col = 4 + (f % 18) * 4; }
        else { int f2 = f - 144; row = 4 + (f2 >> 1); col = (f2 & 1) ? 72 : 4; }
        *(uint2*)&tile[row * DSTR + col] = make_uint2(0u, 0u);
    }
    // interior write from regs (loads landed under the halo fill)
    {
        ushort_t* drow = &tile[(r + 4) * DSTR + 8 + q * 16];
        *(uint2*)(drow + 0)  = make_uint2(ia.x, ia.y);
        *(uint2*)(drow + 4)  = make_uint2(ia.z, ia.w);
        *(uint2*)(drow + 8)  = make_uint2(ib.x, ib.y);
        *(uint2*)(drow + 12) = make_uint2(ib.z, ib.w);
    }
    __syncthreads();

    const int tx = tid & 15, ty = tid >> 4;
    const int x0 = tx * 4, y0 = ty * 4;
    float acc[4][4];
#pragma unroll
    for (int i = 0; i < 4; i++)
#pragma unroll
        for (int j = 0; j < 4; j++) acc[i][j] = 0.f;

    const float* wp = WcP + c * 128;
    float wr[48];

    // window row loader: 12 bf16 from tile cols x0+4 .. x0+15 (3x b64 + unpack)
    auto ldrow = [&](int r6, float* win) {
        const ushort_t* rp = &tile[(y0 + r6) * DSTR + x0 + 4];
        uint2 a = *(const uint2*)rp;
        uint2 b = *(const uint2*)(rp + 4);
        uint2 c2 = *(const uint2*)(rp + 8);
        up2(a.x, win + 0);  up2(a.y, win + 2);
        up2(b.x, win + 4);  up2(b.y, win + 6);
        up2(c2.x, win + 8); up2(c2.y, win + 10);
    };

    // chunk A: dy 0..4 (45 weights), rows y0+0..7
#pragma unroll
    for (int i = 0; i < 12; i++) *(float4*)&wr[4 * i] = *(const float4*)(wp + 4 * i);
#pragma unroll
    for (int r6 = 0; r6 < 8; r6++) {
        float win[12];
        ldrow(r6, win);
#pragma unroll
        for (int yy = 0; yy < 4; yy++) {
            const int d = r6 - yy;
            if (d >= 0 && d <= 4) {
#pragma unroll
                for (int t = 0; t < 9; t++)
#pragma unroll
                    for (int j = 0; j < 4; j++)
                        acc[yy][j] = fmaf(wr[d * 9 + t], win[j + t], acc[yy][j]);
            }
        }
    }
    // chunk B: dy 5..8 (36 weights), rows y0+5..11
#pragma unroll
    for (int i = 0; i < 9; i++) *(float4*)&wr[4 * i] = *(const float4*)(wp + 64 + 4 * i);
#pragma unroll
    for (int r6 = 5; r6 < 12; r6++) {
        float win[12];
        ldrow(r6, win);
#pragma unroll
        for (int yy = 0; yy < 4; yy++) {
            const int d = r6 - yy;
            if (d >= 5 && d <= 8) {
#pragma unroll
                for (int t = 0; t < 9; t++)
#pragma unroll
                    for (int j = 0; j < 4; j++)
                        acc[yy][j] = fmaf(wr[(d - 5) * 9 + t], win[j + t], acc[yy][j]);
            }
        }
    }

    const float bb = biasc[c];
#pragma unroll
    for (int yy = 0; yy < 4; yy++) {
        ushort4 o;
        o.x = f2bf(acc[yy][0] + bb);
        o.y = f2bf(acc[yy][1] + bb);
        o.z = f2bf(acc[yy][2] + bb);
        o.w = f2bf(acc[yy][3] + bb);
        *(ushort4*)&out[plane + (size_t)(y0 + yy) * 64 + x0] = o;
    }
}

// ---------------------------------------------------------------------------
extern "C" void kernel_launch(void* const* d_in, const int* in_sizes, int n_in,
                              void* d_out, int out_size, void* d_ws, size_t ws_size,
                              hipStream_t stream) {
    const float* x     = (const float*)d_in[0];
    const float* pre_w = (const float*)d_in[1];
    const float* bn1g  = (const float*)d_in[2];
    const float* bn1b  = (const float*)d_in[3];
    const float* bn1m  = (const float*)d_in[4];
    const float* bn1v  = (const float*)d_in[5];
    const float* dw3w  = (const float*)d_in[6];
    const float* dw3b  = (const float*)d_in[7];
    const float* dw5w  = (const float*)d_in[8];
    const float* dw5b  = (const float*)d_in[9];
    const float* dw7w  = (const float*)d_in[10];
    const float* dw7b  = (const float*)d_in[11];
    const float* dw9w  = (const float*)d_in[12];
    const float* dw9b  = (const float*)d_in[13];
    const float* pww   = (const float*)d_in[14];
    const float* bn2g  = (const float*)d_in[15];
    const float* bn2b  = (const float*)d_in[16];
    const float* bn2m  = (const float*)d_in[17];
    const float* bn2v  = (const float*)d_in[18];
    const float* postw = (const float*)d_in[19];
    const float* bn3g  = (const float*)d_in[20];
    const float* bn3b  = (const float*)d_in[21];
    const float* bn3m  = (const float*)d_in[22];
    const float* bn3v  = (const float*)d_in[23];

    // Buffers:
    //   h (bf16, 32 MiB)  -> d_out storage (dead before final fp32 write)
    //   s (bf16, 32 MiB)  -> ws[0:32Mi]
    //   aux               -> ws + 33 MiB
    char* wsb = (char*)d_ws;
    ushort_t* sbuf = (ushort_t*)wsb;
    ushort_t* hbuf = (ushort_t*)d_out;
    char* aux = wsb + (size_t)33 * 1024 * 1024;
    ushort_t* w1b = (ushort_t*)aux;
    ushort_t* w2b = w1b + 65536;
    ushort_t* w3b = w2b + 65536;
    float* WcP   = (float*)(w3b + 65536);      // 256*128 fp32
    float* biasc = WcP + 256 * 128;
    float* sc1 = biasc + 256;  float* sh1 = sc1 + 256;
    float* sc2 = sh1 + 256;    float* sh2 = sc2 + 256;
    float* sc3 = sh2 + 256;    float* sh3 = sc3 + 256;

    prep_kernel<<<256, 256, 0, stream>>>(
        pre_w, pww, postw,
        bn1g, bn1b, bn1m, bn1v, bn2g, bn2b, bn2m, bn2v, bn3g, bn3b, bn3m, bn3v,
        dw3w, dw3b, dw5w, dw5b, dw7w, dw7b, dw9w, dw9b,
        w1b, w2b, w3b, WcP, biasc, sc1, sh1, sc2, sh2, sc3, sh3);

    const int nconv = (16 * HW) / TILE;   // 1024 blocks
    // conv1: x fp32 -> h bf16 NCHW (in d_out storage)
    conv_tile<0><<<nconv, 256, 0, stream>>>(x, w1b, sc1, sh1,
                                            nullptr, nullptr, nullptr, hbuf);
    // dw: h -> s bf16 NCHW (in ws)
    dw_kernel<<<16 * CCH, 256, 0, stream>>>(hbuf, WcP, biasc, sbuf);
    // conv2+conv3 fused: s -> out fp32 NCHW (d_out; h dead)
    conv_tile<1><<<nconv, 256, 0, stream>>>(sbuf, w2b, sc2, sh2,
                                            w3b, sc3, sh3, (float*)d_out);
}